// Round 13
// baseline (202.069 us; speedup 1.0000x reference)
//
#include <hip/hip_runtime.h>
#include <float.h>
#include <stdint.h>

// MimiEuclideanCodebook: argmin_k ||x_n - e_k||^2 then gather e_k.
// R21 = R20 (128-row mm, 2-stage barrier intervals, ticket-fused repair)
// with repair restructured K-MAJOR: 64 ksegs x 32 row-stripes = 2048 blocks;
// each block stages its 32-codeword es/u segment into LDS ONCE (32KB) and
// loops over flagged rows (1KB x read each). Old repair re-read the FULL
// 2MB es per flagged row (2-4GB L2 traffic ~ 60-115us, the hidden non-mm
// cost); new traffic = 64MB es + 64*cnt KB x (~30x less). Ticket protocol
// unchanged (64 contributors/row; 64th arriver writes exact e/u row).
// Split-precision virtual K=768: xh*eh + xl*eh + xh*el. Top-2 in registers;
// exact-fp32 repair for rows with gap < DELTA.

#define EPSILON 1e-5f
#define DELTA   1e-3f

constexpr int D     = 256;
constexpr int K_TOT = 2048;

// mm LDS map (halves):
//   0..32768    : prologue A-head regions (8 x 4096); after hoist:
//                 B bufs 4 x 8192 (16KB each)
//   32768..65536: A-resid regions (8 x 4096), persist through main loop
//   65536..69632: esq copy (2048 floats)
constexpr int RES_H      = 32768;
constexpr int ESQ_H      = 65536;
constexpr int LDS_HALVES = 69632;
constexpr int DYN_LDS    = LDS_HALVES * 2;     // 139264 bytes

typedef _Float16 half8v  __attribute__((ext_vector_type(8)));
typedef _Float16 half4v  __attribute__((ext_vector_type(4)));
typedef float    f32x4   __attribute__((ext_vector_type(4)));

#define GLL(SRC, DST)                                                   \
  __builtin_amdgcn_global_load_lds(                                     \
      (const __attribute__((address_space(1))) void*)(SRC),             \
      (__attribute__((address_space(3))) void*)(DST), 16, 0, 0)

// ---------------- prep: ec (half+residual) + esq + counter ----------------
__global__ void prep_kernel(const float* __restrict__ es,
                            const float* __restrict__ usage,
                            _Float16* __restrict__ ec,
                            float* __restrict__ esq,
                            int* __restrict__ counter) {
  const int bx   = blockIdx.x;
  const int t    = threadIdx.x;
  const int wid  = t >> 6;
  const int lane = t & 63;
  if (bx < K_TOT / 4) {
    const int k = bx * 4 + wid;
    const float u = fmaxf(usage[k], EPSILON);
    const float4 v = *(const float4*)(es + (size_t)k * D + lane * 4);
    float4 e;
    e.x = v.x / u; e.y = v.y / u; e.z = v.z / u; e.w = v.w / u;  // exact div
    half4v h, lo;
    h.x = (_Float16)e.x; lo.x = (_Float16)(e.x - (float)h.x);
    h.y = (_Float16)e.y; lo.y = (_Float16)(e.y - (float)h.y);
    h.z = (_Float16)e.z; lo.z = (_Float16)(e.z - (float)h.z);
    h.w = (_Float16)e.w; lo.w = (_Float16)(e.w - (float)h.w);
    *(half4v*)(ec + (size_t)k * 512 + lane * 4)       = h;
    *(half4v*)(ec + (size_t)k * 512 + 256 + lane * 4) = lo;
    float s = e.x * e.x + e.y * e.y + e.z * e.z + e.w * e.w;
    #pragma unroll
    for (int m = 1; m < 64; m <<= 1) s += __shfl_xor(s, m, 64);
    if (lane == 0) esq[k] = s;
  } else {
    if (t == 0) *counter = 0;
  }
}

// ---------------- A-resident MFMA distance GEMM + top-2 + fused gather ----------------
__global__ __launch_bounds__(512, 2)
void mm_kernel(const float* __restrict__ x, const _Float16* __restrict__ ec,
               const float* __restrict__ esq, const float* __restrict__ es,
               const float* __restrict__ usage,
               float* __restrict__ out_q, float* __restrict__ out_i,
               int* __restrict__ list, int* __restrict__ counter,
               unsigned long long* __restrict__ rmin,
               int* __restrict__ tick, int N) {
  extern __shared__ __align__(16) _Float16 lds[];
  const int t    = threadIdx.x;
  const int lane = t & 63;
  const int q    = lane >> 4;
  const int l15  = lane & 15;
  const int wid  = t >> 6;
  const int wn   = wid >> 1;            // 0..3 : 32-row group
  const int wk   = wid & 1;             // 0..1 : 64-col group
  const int n0   = blockIdx.x * 128;

  // ---- esq -> LDS copy (keeps k-tile loop vmem-free) ----
  float* esq_lds = (float*)&lds[ESQ_H];
  {
    const float4 ev = *(const float4*)(esq + t * 4);
    *(float4*)&esq_lds[t * 4] = ev;
  }

  // ---- prologue: x fp32 -> f16 head|resid into swizzled A regions ----
  const int prow  = t >> 2;             // 0..127
  const int pc    = t & 3;              // chunk (8 floats) 0..3
  const int wbase = (t >> 6) * 512 + ((t & 63) ^ ((t >> 3) & 3)) * 8;
  #pragma unroll
  for (int i = 0; i < 8; ++i) {
    const float* src = x + (size_t)(n0 + prow) * D + i * 32 + pc * 8;
    const float4 f0 = *(const float4*)src;
    const float4 f1 = *(const float4*)(src + 4);
    const float f[8] = {f0.x, f0.y, f0.z, f0.w, f1.x, f1.y, f1.z, f1.w};
    half8v hv, lv;
    #pragma unroll
    for (int e = 0; e < 8; ++e) {
      const _Float16 h = (_Float16)f[e];
      hv[e] = h;
      lv[e] = (_Float16)(f[e] - (float)h);   // exact in fp32, then RN to f16
    }
    *(half8v*)&lds[i * 4096 + wbase]         = hv;   // head region (dies)
    *(half8v*)&lds[RES_H + i * 4096 + wbase] = lv;   // resid region (persists)
  }
  __syncthreads();

  // swizzled fragment position (halves) within a 512-half sub-block
  const int gA = l15 * 4 + q;
  const int sp = (gA ^ ((l15 >> 1) & 3)) * 8;

  // ---- hoist A-head fragments to registers (k-invariant, 64 VGPR) ----
  half8v ahr[8][2];
  #pragma unroll
  for (int s = 0; s < 8; ++s)
    #pragma unroll
    for (int mi = 0; mi < 2; ++mi)
      ahr[s][mi] = *(const half8v*)&lds[s * 4096 + wn * 1024 + mi * 512 + sp];
  __syncthreads();   // all waves done with head regions -> B bufs may reuse

  // ---- B staging descriptor: pre-swizzled global source (rule #21) ----
  // Physical slot p = i*512+t holds logical granule (row = p>>3, c = (p&7)^(row&7)).
  const int r0 = t >> 3;                       // rows 0..63 (instr1: +64)
  const int cl = (t & 7) ^ (r0 & 7);
  const _Float16* pB = ec + (size_t)r0 * 512 + cl * 8;

  // prologue DMAs: stages 0,1 into bufs 0,1 (4 GLLs)
  #pragma unroll
  for (int s = 0; s < 2; ++s) {
    const _Float16* sp0 = pB + s * 64;
    GLL(sp0,         &lds[s * 8192 + t * 8]);
    GLL(sp0 + 32768, &lds[s * 8192 + 4096 + t * 8]);
  }

  // B fragment offsets (halves): row cr = wk*64 + ni*16 + l15 (stride 64),
  // granule logical = j*4+q, phys = ^(cr&7) = ^(l15&7).
  int bfoff[4][2];
  #pragma unroll
  for (int ni = 0; ni < 4; ++ni)
    #pragma unroll
    for (int j = 0; j < 2; ++j)
      bfoff[ni][j] = (wk * 64 + ni * 16 + l15) * 64 +
                     (((j << 2) + q) ^ (l15 & 7)) * 8;

  float rd0[2][4], rd1[2][4];
  int   ri0[2][4];
  #pragma unroll
  for (int mi = 0; mi < 2; ++mi)
    #pragma unroll
    for (int r = 0; r < 4; ++r) {
      rd0[mi][r] = FLT_MAX; rd1[mi][r] = FLT_MAX; ri0[mi][r] = 0x7fffffff;
    }

  for (int kt = 0; kt < 16; ++kt) {
    int   kc[4];
    float eqv[4];
    #pragma unroll
    for (int ni = 0; ni < 4; ++ni) {
      kc[ni]  = kt * 128 + wk * 64 + ni * 16 + l15;
      eqv[ni] = esq_lds[kc[ni]];
    }

    f32x4 acc[2][4] = {};

    // 4 intervals per kt; each = 2 stages (BK=64 each) per barrier.
    #pragma unroll
    for (int hv2 = 0; hv2 < 4; ++hv2) {
      const int ivl = kt * 4 + hv2;             // 0..63
      asm volatile("s_waitcnt vmcnt(0)" ::: "memory");
      __builtin_amdgcn_s_barrier();
      __builtin_amdgcn_sched_barrier(0);

      // issue stages 2*ivl+2, 2*ivl+3 into bufs freed in interval ivl-1
      if (ivl < 63) {
        #pragma unroll
        for (int u = 0; u < 2; ++u) {
          const int ns = ivl * 2 + 2 + u;
          const _Float16* np = pB + (size_t)(ns >> 3) * 65536 + (ns & 7) * 64;
          const int nb = (ns & 3) * 8192;
          GLL(np,         &lds[nb + t * 8]);
          GLL(np + 32768, &lds[nb + 4096 + t * 8]);
        }
      }

      __builtin_amdgcn_s_setprio(1);
      #pragma unroll
      for (int u = 0; u < 2; ++u) {
        const int sidx = hv2 * 2 + u;           // 0..7
        const int ss   = kt * 8 + sidx;
        const int bb   = (ss & 3) * 8192;
        #pragma unroll
        for (int j = 0; j < 2; ++j) {
          half8v bf[4];
          #pragma unroll
          for (int ni = 0; ni < 4; ++ni)
            bf[ni] = *(const half8v*)&lds[bb + bfoff[ni][j]];
          const int ks = (sidx & 3) * 2 + j;    // A k-region 0..7
          if (sidx < 4) {
            half8v al[2];
            #pragma unroll
            for (int mi = 0; mi < 2; ++mi)
              al[mi] = *(const half8v*)
                  &lds[RES_H + ks * 4096 + wn * 1024 + mi * 512 + sp];
            #pragma unroll
            for (int mi = 0; mi < 2; ++mi)
              #pragma unroll
              for (int ni = 0; ni < 4; ++ni)
                acc[mi][ni] = __builtin_amdgcn_mfma_f32_16x16x32_f16(
                    ahr[ks][mi], bf[ni], acc[mi][ni], 0, 0, 0);
            #pragma unroll
            for (int mi = 0; mi < 2; ++mi)
              #pragma unroll
              for (int ni = 0; ni < 4; ++ni)
                acc[mi][ni] = __builtin_amdgcn_mfma_f32_16x16x32_f16(
                    al[mi], bf[ni], acc[mi][ni], 0, 0, 0);
          } else {
            #pragma unroll
            for (int mi = 0; mi < 2; ++mi)
              #pragma unroll
              for (int ni = 0; ni < 4; ++ni)
                acc[mi][ni] = __builtin_amdgcn_mfma_f32_16x16x32_f16(
                    ahr[ks][mi], bf[ni], acc[mi][ni], 0, 0, 0);
          }
        }
      }
      __builtin_amdgcn_s_setprio(0);
    }

    // merge this k-tile into running top-2 (ascending k, strict '<')
    #pragma unroll
    for (int ni = 0; ni < 4; ++ni) {
      #pragma unroll
      for (int mi = 0; mi < 2; ++mi) {
        #pragma unroll
        for (int r = 0; r < 4; ++r) {
          const float d = fmaf(-2.f, acc[mi][ni][r], eqv[ni]);
          if (d < rd0[mi][r]) {
            rd1[mi][r] = rd0[mi][r]; rd0[mi][r] = d; ri0[mi][r] = kc[ni];
          } else {
            rd1[mi][r] = fminf(rd1[mi][r], d);
          }
        }
      }
    }
  }
  __syncthreads();   // loop fully drained; B-buf space reusable as exchange

  // cross-lane reduce over 16 k-cols; partials into LDS exchange
  float* ex = (float*)lds;   // [128 rows][2 wk][4 floats] = 4 KB
  #pragma unroll
  for (int mi = 0; mi < 2; ++mi) {
    #pragma unroll
    for (int r = 0; r < 4; ++r) {
      float d0 = rd0[mi][r], d1 = rd1[mi][r];
      int   i0 = ri0[mi][r];
      #pragma unroll
      for (int off = 1; off < 16; off <<= 1) {
        const float od0 = __shfl_xor(d0, off, 16);
        const int   oi0 = __shfl_xor(i0, off, 16);
        const float od1 = __shfl_xor(d1, off, 16);
        if (od0 < d0 || (od0 == d0 && oi0 < i0)) {
          d1 = fminf(d0, od1); d0 = od0; i0 = oi0;
        } else {
          d1 = fminf(d1, od0);
        }
      }
      if (l15 == mi * 8 + r) {
        const int row = wn * 32 + mi * 16 + q * 4 + r;   // 0..127
        *(float4*)&ex[(row * 2 + wk) * 4] =
            make_float4(d0, __int_as_float(i0), d1, 0.f);
      }
    }
  }
  __syncthreads();

  // fused combine + gather: 4 threads per row, 256B each (interleaved float4)
  {
    const int row = t >> 2;        // 0..127
    const int seg = t & 3;
    const float4 a = *(const float4*)&ex[(row * 2 + 0) * 4];
    const float4 b = *(const float4*)&ex[(row * 2 + 1) * 4];
    float d0, d1; int i0;
    const int ia = __float_as_int(a.y), ib = __float_as_int(b.y);
    if (b.x < a.x || (b.x == a.x && ib < ia)) {
      d0 = b.x; i0 = ib; d1 = fminf(a.x, b.z);
    } else {
      d0 = a.x; i0 = ia; d1 = fminf(a.z, b.x);
    }
    const int n = n0 + row;
    const float u  = fmaxf(usage[i0], EPSILON);
    const float4* src = (const float4*)(es + (size_t)i0 * D);
    float4*       dst = (float4*)(out_q + (size_t)n * D);
    #pragma unroll
    for (int i = 0; i < 16; ++i) {
      const int j = i * 4 + seg;
      const float4 e = src[j];
      dst[j] = make_float4(e.x / u, e.y / u, e.z / u, e.w / u);  // exact div
    }
    if (seg == 0) {
      out_i[n] = (float)i0;
      if (d1 - d0 < DELTA) {
        rmin[n] = 0xFFFFFFFFFFFFFFFFull;
        tick[n] = 0;
        const int pos = atomicAdd(counter, 1);
        list[pos] = n;
      }
    }
  }
}

// -------- exact fp32 repair, K-MAJOR: 64 ksegs x 32 row-stripes. --------
// Each block stages 32 codewords of es/u in LDS once, then loops over
// flagged rows. 64 contributors per row; 64th ticket arriver writes row.
__global__ __launch_bounds__(256)
void repair_kernel(const float* __restrict__ x,
                   const float* __restrict__ es,
                   const float* __restrict__ usage,
                   const float* __restrict__ esq,
                   const int* __restrict__ list,
                   const int* __restrict__ counter,
                   unsigned long long* __restrict__ rmin,
                   int* __restrict__ tick,
                   float* __restrict__ out_q,
                   float* __restrict__ out_i) {
  __shared__ float esl[32 * 256];   // 32 KB: es/u segment
  __shared__ float eql[32];
  __shared__ float xs[256];
  __shared__ float bwd[4];
  __shared__ int   bwi[4];
  __shared__ int   bcast;
  const int t    = threadIdx.x;
  const int w    = t >> 6;
  const int lane = t & 63;
  const int kseg = blockIdx.x & 63;        // 64 ksegs of 32 k's
  const int rstr = blockIdx.x >> 6;        // 0..31 row stripes
  const int k0   = kseg * 32;
  const int cnt  = *counter;

  // ---- stage es/u segment (32 k x 256 floats) + esq ----
  #pragma unroll
  for (int i = 0; i < 8; ++i) {
    const int idx = i * 256 + t;           // float4 index 0..2047
    const int kk  = idx >> 6;              // 0..31
    const int c4  = idx & 63;
    const float rs = 1.0f / fmaxf(usage[k0 + kk], EPSILON);
    const float4 e = *(const float4*)(es + (size_t)(k0 + kk) * D + c4 * 4);
    *(float4*)&esl[kk * 256 + c4 * 4] =
        make_float4(e.x * rs, e.y * rs, e.z * rs, e.w * rs);
  }
  if (t < 32) eql[t] = esq[k0 + t];
  __syncthreads();

  for (int j = rstr; j < cnt; j += 32) {
    const int n = list[j];
    xs[t] = x[(size_t)n * D + t];
    __syncthreads();
    const float4 xv = *(const float4*)&xs[lane * 4];

    // wave w handles k's [k0 + w*8, k0 + w*8 + 8)
    float pd[8];
    #pragma unroll
    for (int kk8 = 0; kk8 < 8; ++kk8) {
      const float4 e = *(const float4*)&esl[(w * 8 + kk8) * 256 + lane * 4];
      float p = xv.x * e.x;
      p = fmaf(xv.y, e.y, p);
      p = fmaf(xv.z, e.z, p);
      pd[kk8] = fmaf(xv.w, e.w, p);
    }
    #pragma unroll
    for (int off = 1; off < 64; off <<= 1) {
      #pragma unroll
      for (int kk8 = 0; kk8 < 8; ++kk8)
        pd[kk8] += __shfl_xor(pd[kk8], off, 64);
    }
    float bd = FLT_MAX;
    int   bi = 0x7fffffff;
    #pragma unroll
    for (int kk8 = 0; kk8 < 8; ++kk8) {
      const float dst = fmaf(-2.f, pd[kk8], eql[w * 8 + kk8]);
      if (dst < bd) { bd = dst; bi = k0 + w * 8 + kk8; }   // ascending k
    }
    if (lane == 0) { bwd[w] = bd; bwi[w] = bi; }
    __syncthreads();

    if (t == 0) {
      float d = bwd[0]; int i0 = bwi[0];
      #pragma unroll
      for (int ww = 1; ww < 4; ++ww)
        if (bwd[ww] < d || (bwd[ww] == d && bwi[ww] < i0)) {
          d = bwd[ww]; i0 = bwi[ww];
        }
      uint32_t ub = __float_as_uint(d);
      ub = (ub & 0x80000000u) ? ~ub : (ub | 0x80000000u);
      const unsigned long long pk =
          ((unsigned long long)ub << 32) | (unsigned)i0;
      atomicMin(&rmin[n], pk);
      __threadfence();
      const int done = atomicAdd(&tick[n], 1);
      int widx = -1;
      if (done == 63) {           // last of 64 kseg contributors
        __threadfence();
        const unsigned long long fin = atomicAdd(&rmin[n], 0ull);
        widx = (int)(fin & 0x7fffffffu);
      }
      bcast = widx;
    }
    __syncthreads();
    const int widx = bcast;
    if (widx >= 0) {
      const float u = fmaxf(usage[widx], EPSILON);
      out_q[(size_t)n * D + t] = es[(size_t)widx * D + t] / u;  // exact div
      if (t == 0) out_i[n] = (float)widx;
    }
    __syncthreads();   // protect xs/bcast before next row
  }
}

// ---------------- fallback path (R1, fp32 vector) ----------------
constexpr int TN = 128;
constexpr int DC = 32;
constexpr int KS = 2;
constexpr int RS = 196;

__global__ void esq_kernel(const float* __restrict__ es,
                           const float* __restrict__ usage,
                           float* __restrict__ esq) {
  const int lane = threadIdx.x & 63;
  const int w    = threadIdx.x >> 6;
  const int k    = blockIdx.x * 4 + w;
  const float u  = fmaxf(usage[k], EPSILON);
  const float4 e = *(const float4*)(es + (size_t)k * D + lane * 4);
  const float a = e.x / u, b = e.y / u, c = e.z / u, d = e.w / u;
  float s = a * a + b * b + c * c + d * d;
  #pragma unroll
  for (int m = 1; m < 64; m <<= 1) s += __shfl_xor(s, m, 64);
  if (lane == 0) esq[k] = s;
}

__global__ __launch_bounds__(256, 2)
void dist_kernel(const float* __restrict__ x,
                 const float* __restrict__ es,
                 const float* __restrict__ usage,
                 const float* __restrict__ esq,
                 float* __restrict__ bestd,
                 int* __restrict__ besti, int N) {
  __shared__ float smX[DC * RS];
  __shared__ float smE[DC * RS];
  const int t    = threadIdx.x;
  const int tx   = t & 15;
  const int ty   = t >> 4;
  const int n0   = blockIdx.x * TN;
  const int half = blockIdx.y;

  float best[8];
  int   bidx[8];
  #pragma unroll
  for (int i = 0; i < 8; ++i) { best[i] = FLT_MAX; bidx[i] = 0; }

  for (int kt = 0; kt < (K_TOT / KS) / 128; ++kt) {
    const int k0 = half * (K_TOT / KS) + kt * 128;
    float acc[8][8];
    #pragma unroll
    for (int i = 0; i < 8; ++i)
      #pragma unroll
      for (int j = 0; j < 8; ++j) acc[i][j] = 0.f;

    for (int dc = 0; dc < D; dc += DC) {
      __syncthreads();
      #pragma unroll
      for (int i = 0; i < 4; ++i) {
        const int f    = i * 256 + t;
        const int row  = f >> 3;
        const int c4   = f & 7;
        const int pcol = row + ((row >> 3) << 2);
        const float4 xv =
            *(const float4*)(x + (size_t)(n0 + row) * D + dc + c4 * 4);
        smX[(c4 * 4 + 0) * RS + pcol] = xv.x;
        smX[(c4 * 4 + 1) * RS + pcol] = xv.y;
        smX[(c4 * 4 + 2) * RS + pcol] = xv.z;
        smX[(c4 * 4 + 3) * RS + pcol] = xv.w;
        const int kk = k0 + row;
        const float rs = 1.0f / fmaxf(usage[kk], EPSILON);
        const float4 ev =
            *(const float4*)(es + (size_t)kk * D + dc + c4 * 4);
        smE[(c4 * 4 + 0) * RS + pcol] = ev.x * rs;
        smE[(c4 * 4 + 1) * RS + pcol] = ev.y * rs;
        smE[(c4 * 4 + 2) * RS + pcol] = ev.z * rs;
        smE[(c4 * 4 + 3) * RS + pcol] = ev.w * rs;
      }
      __syncthreads();
      #pragma unroll 4
      for (int d = 0; d < DC; ++d) {
        const float* px = &smX[d * RS + ty * 12];
        const float* pe = &smE[d * RS + tx * 12];
        const float4 xa = *(const float4*)px;
        const float4 xb = *(const float4*)(px + 4);
        const float4 ea = *(const float4*)pe;
        const float4 eb = *(const float4*)(pe + 4);
        const float xr[8] = {xa.x, xa.y, xa.z, xa.w, xb.x, xb.y, xb.z, xb.w};
        const float er[8] = {ea.x, ea.y, ea.z, ea.w, eb.x, eb.y, eb.z, eb.w};
        #pragma unroll
        for (int i = 0; i < 8; ++i)
          #pragma unroll
          for (int jj = 0; jj < 8; ++jj)
            acc[i][jj] = fmaf(xr[i], er[jj], acc[i][jj]);
      }
    }
    #pragma unroll
    for (int jj = 0; jj < 8; ++jj) {
      const int k = k0 + tx * 8 + jj;
      const float eq = esq[k];
      #pragma unroll
      for (int i = 0; i < 8; ++i) {
        const float dst = fmaf(-2.0f, acc[i][jj], eq);
        if (dst < best[i]) { best[i] = dst; bidx[i] = k; }
      }
    }
  }
  __syncthreads();
  float* rd = smX;
  int*   ri = (int*)smE;
  #pragma unroll
  for (int i = 0; i < 8; ++i) {
    const int r = ty * 8 + i;
    rd[tx * TN + r] = best[i];
    ri[tx * TN + r] = bidx[i];
  }
  __syncthreads();
  for (int off = 8; off >= 1; off >>= 1) {
    if (tx < off) {
      #pragma unroll
      for (int i = 0; i < 8; ++i) {
        const int r = ty * 8 + i;
        const float da = rd[tx * TN + r], db = rd[(tx + off) * TN + r];
        const int   ia = ri[tx * TN + r], ib = ri[(tx + off) * TN + r];
        if (db < da || (db == da && ib < ia)) {
          rd[tx * TN + r] = db;
          ri[tx * TN + r] = ib;
        }
      }
    }
    __syncthreads();
  }
  if (tx == 0) {
    #pragma unroll
    for (int i = 0; i < 8; ++i) {
      const int r = ty * 8 + i;
      bestd[(size_t)half * N + n0 + r] = rd[r];
      besti[(size_t)half * N + n0 + r] = ri[r];
    }
  }
}

__global__ void gather_kernel(const float* __restrict__ es,
                              const float* __restrict__ usage,
                              const float* __restrict__ bestd,
                              const int* __restrict__ besti,
                              float* __restrict__ out_q,
                              float* __restrict__ out_i, int N) {
  const int w    = threadIdx.x >> 6;
  const int lane = threadIdx.x & 63;
  const int n    = blockIdx.x * 4 + w;
  const float d0 = bestd[n];
  const float d1 = bestd[(size_t)N + n];
  const int   i0 = besti[n];
  const int   i1 = besti[(size_t)N + n];
  const int idx = (d1 < d0) ? i1 : i0;
  const float u = fmaxf(usage[idx], EPSILON);
  const float4 e = *(const float4*)(es + (size_t)idx * D + lane * 4);
  float4 qv;
  qv.x = e.x / u; qv.y = e.y / u; qv.z = e.z / u; qv.w = e.w / u;
  *(float4*)(out_q + (size_t)n * D + lane * 4) = qv;
  if (lane == 0) out_i[n] = (float)idx;
}

// ---------------- launch ----------------
extern "C" void kernel_launch(void* const* d_in, const int* in_sizes, int n_in,
                              void* d_out, int out_size, void* d_ws, size_t ws_size,
                              hipStream_t stream) {
  const float* x     = (const float*)d_in[0];  // [N, 256]
  const float* es    = (const float*)d_in[1];  // [2048, 256]
  const float* usage = (const float*)d_in[2];  // [2048]
  const int N = in_sizes[0] / D;               // 32768

  float* out_q = (float*)d_out;
  float* out_i = out_q + (size_t)N * D;

  const size_t EB = (size_t)K_TOT * 512 * 2;    // ec: 2 MB
  const size_t off_esq  = EB;
  const size_t off_list = off_esq + 8192;
  const size_t off_cnt  = off_list + (size_t)N * 4;
  const size_t off_rmin = off_cnt + 16;
  const size_t off_tick = off_rmin + (size_t)N * 8;
  const size_t NEED     = off_tick + (size_t)N * 4;

  char* wsb = (char*)d_ws;

  hipError_t attr_ok = hipFuncSetAttribute(
      (const void*)mm_kernel, hipFuncAttributeMaxDynamicSharedMemorySize,
      DYN_LDS);

  if (ws_size >= NEED && attr_ok == hipSuccess && (N % 128) == 0) {
    _Float16* ec   = (_Float16*)wsb;
    float*    esq  = (float*)(wsb + off_esq);
    int*      list = (int*)(wsb + off_list);
    int*      cnt  = (int*)(wsb + off_cnt);
    unsigned long long* rmin = (unsigned long long*)(wsb + off_rmin);
    int*      tick = (int*)(wsb + off_tick);

    prep_kernel<<<K_TOT / 4 + 1, 256, 0, stream>>>(es, usage, ec, esq, cnt);
    mm_kernel<<<N / 128, 512, DYN_LDS, stream>>>(x, ec, esq, es, usage,
                                                 out_q, out_i, list, cnt,
                                                 rmin, tick, N);
    repair_kernel<<<2048, 256, 0, stream>>>(x, es, usage, esq, list, cnt,
                                            rmin, tick, out_q, out_i);
  } else {
    float* ws    = (float*)d_ws;
    float* esq   = ws;
    float* bestd = ws + K_TOT;
    int*   besti = (int*)(ws + K_TOT + (size_t)KS * N);
    esq_kernel<<<K_TOT / 4, 256, 0, stream>>>(es, usage, esq);
    dist_kernel<<<dim3(N / TN, KS), 256, 0, stream>>>(x, es, usage, esq,
                                                      bestd, besti, N);
    gather_kernel<<<N / 4, 256, 0, stream>>>(es, usage, bestd, besti,
                                             out_q, out_i, N);
  }
}